// Round 1
// baseline (264.349 us; speedup 1.0000x reference)
//
#include <hip/hip_runtime.h>
#include <hip/hip_bf16.h>

typedef __attribute__((ext_vector_type(8))) __bf16 bf16x8;
typedef __attribute__((ext_vector_type(4))) float f32x4;

#define ALPHA 0.999f
#define THETA 0.05f

#define K1_BLOCKS 512
#define WPB 4
#define PDY 20
#define PH  36
#define PDH 36
#define PQ  20
#define WAVE_LDS_HALFS (64*(PDY+PH+PDH+PQ))   // 7168 halfs = 14336 B per wave

__device__ __forceinline__ float sigmoidf_(float z){ return 1.f/(1.f+__expf(-z)); }

__device__ __forceinline__ unsigned pk2_(float a, float b){
  union { __bf16 h[2]; unsigned u; } x; x.h[0]=(__bf16)a; x.h[1]=(__bf16)b; return x.u;
}

// ---------------- Kernel 1: gradient pass -> per-block partial sums ----------------
__global__ __launch_bounds__(256, 2)
void k1_grad(const float* __restrict__ X,
             const float* __restrict__ W0, const float* __restrict__ b0,
             const float* __restrict__ W1, const float* __restrict__ b1,
             const float* __restrict__ WV, const float* __restrict__ WQ,
             float* __restrict__ wsPart, int N)
{
  __shared__ __align__(16) __bf16 smem[WPB*WAVE_LDS_HALFS + 32];
  const int tid = threadIdx.x;
  const int w = tid >> 6, l = tid & 63;
  __bf16* DY = smem + w*WAVE_LDS_HALFS;
  __bf16* DH = DY + 64*PDY;
  __bf16* H  = DH + 64*PDH;
  __bf16* Q  = H  + 64*PH;

  // ones-column + zero pads (cols never overwritten by row stores)
  H[l*PH+32]=(__bf16)1.f; H[l*PH+33]=(__bf16)0.f; H[l*PH+34]=(__bf16)0.f; H[l*PH+35]=(__bf16)0.f;
  Q[l*PQ+16]=(__bf16)1.f; Q[l*PQ+17]=(__bf16)0.f; Q[l*PQ+18]=(__bf16)0.f; Q[l*PQ+19]=(__bf16)0.f;

  f32x4 acc[7] = {};

  const int nb = N >> 6;                 // 64-row batches
  const int tw = K1_BLOCKS*WPB;          // total waves
  const int gw = blockIdx.x*WPB + w;
  const int iters = (nb + tw - 1) / tw;

  for (int it = 0; it < iters; ++it) {
    const int batch = gw + it*tw;
    const bool active = (batch < nb);

    if (active) {
      const int row = (batch<<6) + l;
      const float* xp = X + (size_t)row*16;
      float x[16];
      {
        const float4* xv = (const float4*)xp;
        float4 t0=xv[0], t1=xv[1], t2=xv[2], t3=xv[3];
        x[0]=t0.x; x[1]=t0.y; x[2]=t0.z; x[3]=t0.w;
        x[4]=t1.x; x[5]=t1.y; x[6]=t1.z; x[7]=t1.w;
        x[8]=t2.x; x[9]=t2.y; x[10]=t2.z; x[11]=t2.w;
        x[12]=t3.x; x[13]=t3.y; x[14]=t3.z; x[15]=t3.w;
      }
      // v = silu(x @ WV^T)
      float vv[16];
      #pragma unroll
      for (int k=0;k<16;++k){
        float s = 0.f;
        #pragma unroll
        for (int d=0;d<16;++d) s = fmaf(x[d], WV[k*16+d], s);
        vv[k] = s * sigmoidf_(s);
      }
      // q = l2norm(silu(x @ WQ^T))
      float q[16]; float n2 = 0.f;
      #pragma unroll
      for (int k=0;k<16;++k){
        float s = 0.f;
        #pragma unroll
        for (int d=0;d<16;++d) s = fmaf(x[d], WQ[k*16+d], s);
        float t = s * sigmoidf_(s);
        q[k] = t; n2 = fmaf(t, t, n2);
      }
      const float inv = 1.f / fmaxf(sqrtf(n2), 1e-12f);
      #pragma unroll
      for (int k=0;k<16;++k) q[k] *= inv;
      // h = silu(q @ W0^T + b0), keep dsilu
      float h[32], dsh[32];
      #pragma unroll
      for (int j=0;j<32;++j){
        float s = b0[j];
        #pragma unroll
        for (int d=0;d<16;++d) s = fmaf(q[d], W0[j*16+d], s);
        float sg = sigmoidf_(s);
        h[j] = s*sg;
        dsh[j] = sg * fmaf(s, 1.f - sg, 1.f);
      }
      // y, dy (unscaled: scale 2/(N*16) applied in k2)
      float dy[16];
      #pragma unroll
      for (int k=0;k<16;++k){
        float s = b1[k];
        #pragma unroll
        for (int j=0;j<32;++j) s = fmaf(h[j], W1[k*32+j], s);
        float sg = sigmoidf_(s);
        float y = s*sg;
        float ds = sg * fmaf(s, 1.f - sg, 1.f);
        dy[k] = (y - vv[k]) * ds;
      }
      // dh
      float dh[32];
      #pragma unroll
      for (int j=0;j<32;++j){
        float s = 0.f;
        #pragma unroll
        for (int k=0;k<16;++k) s = fmaf(dy[k], W1[k*32+j], s);
        dh[j] = s * dsh[j];
      }
      // stage rows (bf16) into this wave's LDS region
      {
        uint2* p = (uint2*)(DY + (size_t)l*PDY);
        #pragma unroll
        for (int k=0;k<16;k+=4) p[k>>2] = make_uint2(pk2_(dy[k],dy[k+1]), pk2_(dy[k+2],dy[k+3]));
      }
      {
        uint2* p = (uint2*)(DH + (size_t)l*PDH);
        #pragma unroll
        for (int j=0;j<32;j+=4) p[j>>2] = make_uint2(pk2_(dh[j],dh[j+1]), pk2_(dh[j+2],dh[j+3]));
      }
      {
        uint2* p = (uint2*)(H + (size_t)l*PH);
        #pragma unroll
        for (int j=0;j<32;j+=4) p[j>>2] = make_uint2(pk2_(h[j],h[j+1]), pk2_(h[j+2],h[j+3]));
      }
      {
        uint2* p = (uint2*)(Q + (size_t)l*PQ);
        #pragma unroll
        for (int k=0;k<16;k+=4) p[k>>2] = make_uint2(pk2_(q[k],q[k+1]), pk2_(q[k+2],q[k+3]));
      }
    }
    __syncthreads();
    if (active) {
      const int c = l & 15;
      #pragma unroll
      for (int kc=0;kc<2;++kc){
        const int r0 = (kc<<5) + ((l>>4)<<3);
        const __bf16* pdy = DY + r0*PDY + c;
        const __bf16* ph  = H  + r0*PH  + c;
        const __bf16* pdh = DH + r0*PDH + c;
        const __bf16* pq  = Q  + r0*PQ  + c;
        bf16x8 fdy, fh0, fh1, fhb, fd0, fd1, fq0, fqb;
        #pragma unroll
        for (int i=0;i<8;++i){
          fdy[i] = pdy[i*PDY];
          fh0[i] = ph[i*PH];
          fh1[i] = ph[i*PH + 16];
          fhb[i] = ph[i*PH + 32];
          fd0[i] = pdh[i*PDH];
          fd1[i] = pdh[i*PDH + 16];
          fq0[i] = pq[i*PQ];
          fqb[i] = pq[i*PQ + 16];
        }
        acc[0] = __builtin_amdgcn_mfma_f32_16x16x32_bf16(fdy, fh0, acc[0], 0,0,0); // gW1[:, 0:16]
        acc[1] = __builtin_amdgcn_mfma_f32_16x16x32_bf16(fdy, fh1, acc[1], 0,0,0); // gW1[:,16:32]
        acc[2] = __builtin_amdgcn_mfma_f32_16x16x32_bf16(fdy, fhb, acc[2], 0,0,0); // gb1 (col 0)
        acc[3] = __builtin_amdgcn_mfma_f32_16x16x32_bf16(fd0, fq0, acc[3], 0,0,0); // gW0[0:16, :]
        acc[4] = __builtin_amdgcn_mfma_f32_16x16x32_bf16(fd1, fq0, acc[4], 0,0,0); // gW0[16:32,:]
        acc[5] = __builtin_amdgcn_mfma_f32_16x16x32_bf16(fd0, fqb, acc[5], 0,0,0); // gb0[0:16] (col 0)
        acc[6] = __builtin_amdgcn_mfma_f32_16x16x32_bf16(fd1, fqb, acc[6], 0,0,0); // gb0[16:32] (col 0)
      }
    }
    __syncthreads();
  }

  // block reduction over the 4 waves (reuse LDS as float)
  float* red = (float*)smem;
  #pragma unroll
  for (int a=0;a<7;++a){
    #pragma unroll
    for (int r=0;r<4;++r)
      red[w*1792 + a*256 + l*4 + r] = acc[a][r];
  }
  __syncthreads();
  for (int s = tid; s < 1792; s += 256){
    float sum = red[s] + red[1792+s] + red[2*1792+s] + red[3*1792+s];
    wsPart[(size_t)blockIdx.x*1792 + s] = sum;
  }
}

// ---------------- Kernel 2: reduce partials, form updated params ----------------
__global__ void k2_reduce(const float* __restrict__ wsPart,
                          const float* __restrict__ W0, const float* __restrict__ b0,
                          const float* __restrict__ W1, const float* __restrict__ b1,
                          float* __restrict__ P, float scale)
{
  int s = blockIdx.x*256 + threadIdx.x;
  if (s >= 1792) return;
  float g = 0.f;
  for (int b=0;b<K1_BLOCKS;++b) g += wsPart[(size_t)b*1792 + s];
  g *= scale;   // 2/(N*16)
  int a = s >> 8, l = (s >> 2) & 63, r = s & 3;
  int m = ((l>>4)<<2) + r, n = l & 15;
  // P layout (floats): W0[0..511], b0[512..543], W1[544..1055], b1[1056..1071]
  if (a==0)      P[544 + m*32 + n]       = ALPHA*W1[m*32+n]        - THETA*g;
  else if (a==1) P[544 + m*32 + 16 + n]  = ALPHA*W1[m*32+16+n]     - THETA*g;
  else if (a==2){ if (n==0) P[1056 + m]  = ALPHA*b1[m]             - THETA*g; }
  else if (a==3) P[m*16 + n]             = ALPHA*W0[m*16+n]        - THETA*g;
  else if (a==4) P[(16+m)*16 + n]        = ALPHA*W0[(16+m)*16+n]   - THETA*g;
  else if (a==5){ if (n==0) P[512 + m]   = ALPHA*b0[m]             - THETA*g; }
  else           { if (n==0) P[512+16+m] = ALPHA*b0[16+m]          - THETA*g; }
}

// ---------------- Kernel 3: retrieve pass ----------------
__global__ __launch_bounds__(256)
void k3_retrieve(const float* __restrict__ X, const float* __restrict__ WQ,
                 const float* __restrict__ P, float* __restrict__ out, int N)
{
  int row = blockIdx.x*256 + threadIdx.x;
  if (row >= N) return;
  const float* xp = X + (size_t)row*16;
  float x[16];
  {
    const float4* xv = (const float4*)xp;
    float4 t0=xv[0], t1=xv[1], t2=xv[2], t3=xv[3];
    x[0]=t0.x; x[1]=t0.y; x[2]=t0.z; x[3]=t0.w;
    x[4]=t1.x; x[5]=t1.y; x[6]=t1.z; x[7]=t1.w;
    x[8]=t2.x; x[9]=t2.y; x[10]=t2.z; x[11]=t2.w;
    x[12]=t3.x; x[13]=t3.y; x[14]=t3.z; x[15]=t3.w;
  }
  // r = silu(l2norm(x @ WQ^T))   (note: norm BEFORE silu here)
  float rq[16]; float n2 = 0.f;
  #pragma unroll
  for (int k=0;k<16;++k){
    float s = 0.f;
    #pragma unroll
    for (int d=0;d<16;++d) s = fmaf(x[d], WQ[k*16+d], s);
    rq[k] = s; n2 = fmaf(s, s, n2);
  }
  const float inv = 1.f / fmaxf(sqrtf(n2), 1e-12f);
  #pragma unroll
  for (int k=0;k<16;++k){
    float z = rq[k]*inv;
    rq[k] = z * sigmoidf_(z);
  }
  // h = silu(r @ W0'^T + b0')
  float h[32];
  #pragma unroll
  for (int j=0;j<32;++j){
    float s = P[512+j];
    #pragma unroll
    for (int d=0;d<16;++d) s = fmaf(rq[d], P[j*16+d], s);
    h[j] = s * sigmoidf_(s);
  }
  // o = silu(h @ W1'^T + b1')
  float o[16];
  #pragma unroll
  for (int k=0;k<16;++k){
    float s = P[1056+k];
    #pragma unroll
    for (int j=0;j<32;++j) s = fmaf(h[j], P[544 + k*32 + j], s);
    o[k] = s * sigmoidf_(s);
  }
  float4* op = (float4*)(out + (size_t)row*16);
  op[0] = make_float4(o[0],o[1],o[2],o[3]);
  op[1] = make_float4(o[4],o[5],o[6],o[7]);
  op[2] = make_float4(o[8],o[9],o[10],o[11]);
  op[3] = make_float4(o[12],o[13],o[14],o[15]);
}

extern "C" void kernel_launch(void* const* d_in, const int* in_sizes, int n_in,
                              void* d_out, int out_size, void* d_ws, size_t ws_size,
                              hipStream_t stream)
{
  const float* X  = (const float*)d_in[0];
  const float* W0 = (const float*)d_in[1];
  const float* b0 = (const float*)d_in[2];
  const float* W1 = (const float*)d_in[3];
  const float* b1 = (const float*)d_in[4];
  const float* WV = (const float*)d_in[6];
  const float* WQ = (const float*)d_in[7];
  float* ws   = (float*)d_ws;
  float* P    = ws;           // 1072 floats of updated params
  float* part = ws + 2048;    // 512*1792 floats of partials

  const int N = in_sizes[0] / 16;
  const float scale = 2.f / (16.f * (float)N);

  k1_grad<<<dim3(K1_BLOCKS), dim3(256), 0, stream>>>(X, W0, b0, W1, b1, WV, WQ, part, N);
  k2_reduce<<<dim3(7), dim3(256), 0, stream>>>(part, W0, b0, W1, b1, P, scale);
  k3_retrieve<<<dim3((N+255)/256), dim3(256), 0, stream>>>(X, WQ, P, (float*)d_out, N);
}